// Round 3
// baseline (119.597 us; speedup 1.0000x reference)
//
#include <hip/hip_runtime.h>

// CIN layer fused, round 3: kill LDS broadcasts.
//
// out[b,n,w] = bias[n] + sum_{r,j} x0[b, w&31, 2r+h] * xk[b, j, 2r+h] * W[n,r,j],  h = w>>5
//   phase B: G[n, h, r] = sum_j W[n,r,j] * xk[b, j, 2r+h]   (W in VGPRs, xk via
//            wave-uniform scalar loads from global -- zero LDS traffic)
//   phase C: out[b,n,w] = bias[n] + sum_r x0T[2r+h][w&31] * G[n,h,r]
//            (4n x 8w register tiles, x0T swizzled, Gt[hr][n] layout -> all reads
//             <=2-way bank conflict)
//
// One 1024-thread block per CU (grid 256), 4 batches per block, LDS 50 KB.

constexpr int ST0 = 36;   // x0T row stride (words), 16B-aligned, pad vs power-of-2

__global__ __launch_bounds__(1024, 4)
void cin_fused(const float* __restrict__ x0,
               const float* __restrict__ xk,
               const float* __restrict__ W,
               const float* __restrict__ bias,
               float* __restrict__ out)
{
    __shared__ __align__(16) float x0T[2][64 * ST0];  // 18 KB: one batch-PAIR, [fi][t^swz]
    __shared__ __align__(16) float Gt[2][64 * 64];    // 32 KB: Gt[kb][h*32+r][n]

    const int tid = threadIdx.x;
    const int b0  = blockIdx.x * 4;
    const int n   = tid & 63;          // lane = filter index
    const int wv  = tid >> 6;          // wave 0..15
    const int r0  = 2 * wv;            // this thread's W rows: r0, r0+1

    // ---- W rows r0, r0+1 of filter n -> 64 VGPRs (read once, reused x4 batches)
    float w0reg[32], w1reg[32];
    {
        const float4* wp = reinterpret_cast<const float4*>(W + ((size_t)n * 32 + r0) * 32);
        #pragma unroll
        for (int q = 0; q < 8; ++q) {
            const float4 a = wp[q];
            w0reg[4*q+0] = a.x; w0reg[4*q+1] = a.y; w0reg[4*q+2] = a.z; w0reg[4*q+3] = a.w;
        }
        #pragma unroll
        for (int q = 0; q < 8; ++q) {
            const float4 b = wp[8 + q];
            w1reg[4*q+0] = b.x; w1reg[4*q+1] = b.y; w1reg[4*q+2] = b.z; w1reg[4*q+3] = b.w;
        }
    }

    // ---- x0 staging map (one float4/thread per batch-pair)
    const int skb = tid >> 9;                 // batch-in-pair 0/1
    const int su  = tid & 511;                // float4 index within the batch
    const int st  = su >> 4;                  // source row t
    const int sf4 = su & 15;                  // fi0 = 4*sf4
    const int sts = st ^ (4 * (sf4 & 7));     // swizzled t (write <=2-way, read conflict-free)

    // pair-0 x0 global load (coalesced)
    const float4 s0 = reinterpret_cast<const float4*>(x0 + (size_t)(b0 + skb) * 2048)[su];

    // wave-uniform wave id for scalar xk addressing
    const int gu = __builtin_amdgcn_readfirstlane(wv);

    // phase B kernel: G for rows r0,r0+1, both h, one batch; xk via uniform loads
    auto phaseB = [&](int kb, float g4[4]) {
        const float4* pk4 = reinterpret_cast<const float4*>(
            xk + (size_t)(b0 + kb) * 2048 + 4 * gu);   // uniform pointer -> s_load
        float a00 = 0.f, a01 = 0.f, a10 = 0.f, a11 = 0.f;
        #pragma unroll
        for (int j = 0; j < 32; ++j) {
            const float4 kv = pk4[(size_t)j * 16];     // xk[j][4g .. 4g+3]
            a00 = fmaf(w0reg[j], kv.x, a00);           // (r0,   h=0)
            a01 = fmaf(w0reg[j], kv.y, a01);           // (r0,   h=1)
            a10 = fmaf(w1reg[j], kv.z, a10);           // (r0+1, h=0)
            a11 = fmaf(w1reg[j], kv.w, a11);           // (r0+1, h=1)
        }
        g4[0] = a00; g4[1] = a01; g4[2] = a10; g4[3] = a11;
    };
    auto writeG = [&](int buf, const float g4[4]) {    // lanes n stride-1: conflict-free
        Gt[buf][(r0     ) * 64 + n] = g4[0];
        Gt[buf][(32 + r0) * 64 + n] = g4[1];
        Gt[buf][(r0 + 1 ) * 64 + n] = g4[2];
        Gt[buf][(33 + r0) * 64 + n] = g4[3];
    };

    // phase C: 4 waves, each thread 4n x 8w of one batch in the pair
    auto phaseC = [&](int bbase) {
        const int kb   = wv & 1;
        const int nBlk = wv >> 1;              // 0..1 (only wv<4 here)
        const int l    = tid & 63;
        const int wGrp = l & 7;
        const int nGrp = l >> 3;
        const int n0   = nBlk * 32 + nGrp * 4;
        const int w0   = wGrp * 8;             // stays within one h-half
        const int h    = w0 >> 5;
        const int t0   = w0 & 31;
        const float4 bv = *reinterpret_cast<const float4*>(bias + n0);
        float acc[4][8];
        #pragma unroll
        for (int e = 0; e < 4; ++e) {
            const float be = (e == 0) ? bv.x : (e == 1) ? bv.y : (e == 2) ? bv.z : bv.w;
            #pragma unroll
            for (int i = 0; i < 8; ++i) acc[e][i] = be;
        }
        #pragma unroll
        for (int r = 0; r < 32; ++r) {
            const int swz = 4 * ((r >> 1) & 7);        // matches staging (fi>>2 = r>>1)
            const float* xrow = &x0T[kb][(2 * r + h) * ST0];
            const float4 xa = *reinterpret_cast<const float4*>(&xrow[t0 ^ swz]);
            const float4 xb = *reinterpret_cast<const float4*>(&xrow[(t0 + 4) ^ swz]);
            const float4 gv = *reinterpret_cast<const float4*>(&Gt[kb][(h * 32 + r) * 64 + n0]);
            #pragma unroll
            for (int e = 0; e < 4; ++e) {
                const float ge = (e == 0) ? gv.x : (e == 1) ? gv.y : (e == 2) ? gv.z : gv.w;
                acc[e][0] = fmaf(ge, xa.x, acc[e][0]);
                acc[e][1] = fmaf(ge, xa.y, acc[e][1]);
                acc[e][2] = fmaf(ge, xa.z, acc[e][2]);
                acc[e][3] = fmaf(ge, xa.w, acc[e][3]);
                acc[e][4] = fmaf(ge, xb.x, acc[e][4]);
                acc[e][5] = fmaf(ge, xb.y, acc[e][5]);
                acc[e][6] = fmaf(ge, xb.z, acc[e][6]);
                acc[e][7] = fmaf(ge, xb.w, acc[e][7]);
            }
        }
        float* ob = out + (size_t)(bbase + kb) * 4096;
        #pragma unroll
        for (int e = 0; e < 4; ++e) {
            *reinterpret_cast<float4*>(&ob[(n0 + e) * 64 + w0]) =
                make_float4(acc[e][0], acc[e][1], acc[e][2], acc[e][3]);
            *reinterpret_cast<float4*>(&ob[(n0 + e) * 64 + w0 + 4]) =
                make_float4(acc[e][4], acc[e][5], acc[e][6], acc[e][7]);
        }
    };

    // ---- schedule: 3 barriers total ----
    // commit pair-0 x0T
    {
        float* row = &x0T[skb][(4 * sf4) * ST0];
        row[0 * ST0 + sts] = s0.x; row[1 * ST0 + sts] = s0.y;
        row[2 * ST0 + sts] = s0.z; row[3 * ST0 + sts] = s0.w;
    }
    // phase B for batches 0,1 (no LDS reads -> no barrier needed before)
    float gA[4];
    phaseB(0, gA); writeG(0, gA);
    phaseB(1, gA); writeG(1, gA);
    __syncthreads();                       // x0T pair-0 + Gt 0/1 visible

    // phase B for batches 2,3 into registers; prefetch pair-1 x0; then C(0,1)
    float gC[4], gD[4];
    phaseB(2, gC);
    phaseB(3, gD);
    const float4 s1 = reinterpret_cast<const float4*>(x0 + (size_t)(b0 + 2 + skb) * 2048)[su];
    if (wv < 4) phaseC(b0);
    __syncthreads();                       // C(0,1) reads done -> buffers reusable

    // commit pair-1 x0T + Gt 2/3
    {
        float* row = &x0T[skb][(4 * sf4) * ST0];
        row[0 * ST0 + sts] = s1.x; row[1 * ST0 + sts] = s1.y;
        row[2 * ST0 + sts] = s1.z; row[3 * ST0 + sts] = s1.w;
    }
    writeG(0, gC);
    writeG(1, gD);
    __syncthreads();                       // pair-1 visible

    if (wv < 4) phaseC(b0 + 2);
}

extern "C" void kernel_launch(void* const* d_in, const int* in_sizes, int n_in,
                              void* d_out, int out_size, void* d_ws, size_t ws_size,
                              hipStream_t stream) {
    const float* x0   = (const float*)d_in[0];
    const float* xk   = (const float*)d_in[1];
    const float* W    = (const float*)d_in[2];
    const float* bias = (const float*)d_in[3];
    float* out = (float*)d_out;

    cin_fused<<<dim3(256), dim3(1024), 0, stream>>>(x0, xk, W, bias, out);
}

// Round 5
// 90.542 us; speedup vs baseline: 1.3209x; 1.3209x over previous
//
#include <hip/hip_runtime.h>

// CIN layer fused, round 4 (resubmit -- R4 bench was a GPU-acquisition timeout,
// kernel never ran): W register-resident with PINNED 128-VGPR budget
// (amdgpu_waves_per_eu(4,4) -- R3 spilled because launch_bounds' min-waves
// arg let RA target 8 waves/EU = 64 VGPRs).
//
// out[b,n,w] = bias[n] + sum_{r,j} x0[b, w&31, 2r+h] * xk[b, j, 2r+h] * W[n,r,j],  h=w>>5
//   phase B: G[n,h,r] = sum_j W[n,r,j] * xk[b,j,2r+h]
//            thread (n, wv) owns W rows {2wv, 2wv+1} (64 VGPR, loaded once per
//            block = once per 4 batches). xk read as ONE wave-uniform b128 per j:
//            xk[j][4wv..4wv+3] = (r0h0, r0h1, r1h0, r1h1) -- broadcast, conflict-free.
//   phase C: out = bias + x0T^T * G, 4n x 4w register tile per thread,
//            2 x b128 LDS reads per 16 FMA, all patterns <=2-way.
//
// Grid 256 x 1024 threads, 4 batches/block, 132 KB LDS (1 block/CU), 2 barriers.

constexpr int ST0 = 36;   // x0T row stride (words): 16B-aligned, XOR-swizzled t

__global__ __launch_bounds__(1024)
__attribute__((amdgpu_waves_per_eu(4, 4)))
void cin_fused(const float* __restrict__ x0,
               const float* __restrict__ xk,
               const float* __restrict__ W,
               const float* __restrict__ bias,
               float* __restrict__ out)
{
    __shared__ __align__(16) float xkL[4][32 * 64];   // 32 KB [kb][j][fi] linear
    __shared__ __align__(16) float x0T[4][64 * ST0];  // 36 KB [kb][fi][t^swz]
    __shared__ __align__(16) float Gt[4][64 * 64];    // 64 KB [kb][h*32+r][n]

    const int tid = threadIdx.x;
    const int b0  = blockIdx.x * 4;
    const int n   = tid & 63;
    const int wv  = tid >> 6;
    const int r0  = 2 * wv;

    // ---- issue staging loads (coalesced; f4 #tid and #tid+1024 of each 8K-slab)
    const float4* xksrc = reinterpret_cast<const float4*>(xk + (size_t)b0 * 2048);
    const float4* x0src = reinterpret_cast<const float4*>(x0 + (size_t)b0 * 2048);
    const float4 k0 = xksrc[tid];
    const float4 k1 = xksrc[tid + 1024];
    const float4 a0 = x0src[tid];
    const float4 a1 = x0src[tid + 1024];

    // ---- W rows r0, r0+1 of filter n -> 64 VGPRs (once per block)
    float w0reg[32], w1reg[32];
    {
        const float4* wp = reinterpret_cast<const float4*>(W + ((size_t)n * 32 + r0) * 32);
        #pragma unroll
        for (int q = 0; q < 8; ++q) {
            const float4 v = wp[q];
            w0reg[4*q+0] = v.x; w0reg[4*q+1] = v.y; w0reg[4*q+2] = v.z; w0reg[4*q+3] = v.w;
        }
        #pragma unroll
        for (int q = 0; q < 8; ++q) {
            const float4 v = wp[8 + q];
            w1reg[4*q+0] = v.x; w1reg[4*q+1] = v.y; w1reg[4*q+2] = v.z; w1reg[4*q+3] = v.w;
        }
    }

    // ---- commit staged data to LDS
    {
        const int kb = tid >> 9;        // 0 or 1; second load is kb+2
        const int u  = tid & 511;       // f4 index within batch
        // xk: linear b128 writes, conflict-free
        reinterpret_cast<float4*>(xkL[kb    ])[u] = k0;
        reinterpret_cast<float4*>(xkL[kb + 2])[u] = k1;
        // x0: transposed scalar writes, swizzled (<=2-way)
        const int st  = u >> 4;                  // source row t
        const int sf4 = u & 15;                  // fi0 = 4*sf4
        const int sts = st ^ (4 * (sf4 & 7));    // XOR swizzle
        float* r0w = &x0T[kb    ][(4 * sf4) * ST0];
        float* r1w = &x0T[kb + 2][(4 * sf4) * ST0];
        r0w[0 * ST0 + sts] = a0.x; r0w[1 * ST0 + sts] = a0.y;
        r0w[2 * ST0 + sts] = a0.z; r0w[3 * ST0 + sts] = a0.w;
        r1w[0 * ST0 + sts] = a1.x; r1w[1 * ST0 + sts] = a1.y;
        r1w[2 * ST0 + sts] = a1.z; r1w[3 * ST0 + sts] = a1.w;
    }
    __syncthreads();

    // ---- phase B: G for rows r0,r0+1, both h, 4 batches
    for (int kb = 0; kb < 4; ++kb) {
        const float* p = &xkL[kb][4 * wv];
        float a00 = 0.f, a01 = 0.f, a10 = 0.f, a11 = 0.f;
        #pragma unroll
        for (int q = 0; q < 4; ++q) {       // 8-j groups bound live xk regs
            float4 kv[8];
            #pragma unroll
            for (int m = 0; m < 8; ++m)
                kv[m] = *reinterpret_cast<const float4*>(p + (q * 8 + m) * 64);
            #pragma unroll
            for (int m = 0; m < 8; ++m) {
                const int j = q * 8 + m;
                a00 = fmaf(w0reg[j], kv[m].x, a00);   // (r0,   h=0)
                a01 = fmaf(w0reg[j], kv[m].y, a01);   // (r0,   h=1)
                a10 = fmaf(w1reg[j], kv[m].z, a10);   // (r0+1, h=0)
                a11 = fmaf(w1reg[j], kv[m].w, a11);   // (r0+1, h=1)
            }
        }
        Gt[kb][(r0     ) * 64 + n] = a00;   // lanes n stride-1: conflict-free
        Gt[kb][(32 + r0) * 64 + n] = a01;
        Gt[kb][(r0 + 1 ) * 64 + n] = a10;
        Gt[kb][(33 + r0) * 64 + n] = a11;
    }
    __syncthreads();

    // ---- phase C: each thread one batch (kb = tid>>8), 4n x 4w tile
    {
        const int kb = tid >> 8;
        const int t2 = tid & 255;
        const int n0 = (t2 >> 4) * 4;
        const int w0 = (t2 & 15) * 4;
        const int h  = w0 >> 5;
        const int t0 = w0 & 31;

        const float4 bv = *reinterpret_cast<const float4*>(bias + n0);
        float acc[4][4];
        #pragma unroll
        for (int i = 0; i < 4; ++i) { acc[0][i] = bv.x; acc[1][i] = bv.y; acc[2][i] = bv.z; acc[3][i] = bv.w; }

        #pragma unroll
        for (int r = 0; r < 32; ++r) {
            const int swz = 4 * ((r >> 1) & 7);    // matches staging (fi>>2 = r>>1)
            const float4 xv = *reinterpret_cast<const float4*>(
                &x0T[kb][(2 * r + h) * ST0 + (t0 ^ swz)]);
            const float4 gv = *reinterpret_cast<const float4*>(
                &Gt[kb][(h * 32 + r) * 64 + n0]);
            acc[0][0] = fmaf(gv.x, xv.x, acc[0][0]);
            acc[0][1] = fmaf(gv.x, xv.y, acc[0][1]);
            acc[0][2] = fmaf(gv.x, xv.z, acc[0][2]);
            acc[0][3] = fmaf(gv.x, xv.w, acc[0][3]);
            acc[1][0] = fmaf(gv.y, xv.x, acc[1][0]);
            acc[1][1] = fmaf(gv.y, xv.y, acc[1][1]);
            acc[1][2] = fmaf(gv.y, xv.z, acc[1][2]);
            acc[1][3] = fmaf(gv.y, xv.w, acc[1][3]);
            acc[2][0] = fmaf(gv.z, xv.x, acc[2][0]);
            acc[2][1] = fmaf(gv.z, xv.y, acc[2][1]);
            acc[2][2] = fmaf(gv.z, xv.z, acc[2][2]);
            acc[2][3] = fmaf(gv.z, xv.w, acc[2][3]);
            acc[3][0] = fmaf(gv.w, xv.x, acc[3][0]);
            acc[3][1] = fmaf(gv.w, xv.y, acc[3][1]);
            acc[3][2] = fmaf(gv.w, xv.z, acc[3][2]);
            acc[3][3] = fmaf(gv.w, xv.w, acc[3][3]);
        }

        float* ob = out + (size_t)(b0 + kb) * 4096;
        #pragma unroll
        for (int e = 0; e < 4; ++e) {
            *reinterpret_cast<float4*>(&ob[(n0 + e) * 64 + w0]) =
                make_float4(acc[e][0], acc[e][1], acc[e][2], acc[e][3]);
        }
    }
}

extern "C" void kernel_launch(void* const* d_in, const int* in_sizes, int n_in,
                              void* d_out, int out_size, void* d_ws, size_t ws_size,
                              hipStream_t stream) {
    const float* x0   = (const float*)d_in[0];
    const float* xk   = (const float*)d_in[1];
    const float* W    = (const float*)d_in[2];
    const float* bias = (const float*)d_in[3];
    float* out = (float*)d_out;

    cin_fused<<<dim3(256), dim3(1024), 0, stream>>>(x0, xk, W, bias, out);
}